// Round 6
// baseline (2450.143 us; speedup 1.0000x reference)
//
#include <hip/hip_runtime.h>
#include <hip/hip_cooperative_groups.h>

namespace cg = cooperative_groups;

#define NB 4
#define NT 8192
#define NC 64
#define NS 256
#define NV 256
#define NL 30

typedef __attribute__((ext_vector_type(8))) short bf16x8;
typedef __attribute__((ext_vector_type(4))) float f32x4;
typedef unsigned short ushort_t;

#define MFMA(a, b, c) __builtin_amdgcn_mfma_f32_16x16x32_bf16(a, b, c, 0, 0, 0)

// weight arena layout (bf16 elements)
#define OFF_WCAT 0
#define SZ_WCAT  (NL * 16384)                 // swizzled [l][kk=4][n=128][j=32]
#define OFF_RW   (OFF_WCAT + SZ_WCAT)
#define SZ_RW    (NL * 4096)                  // swizzled [l][kk=2][n=64][j=32]
#define OFF_SW   (OFF_RW + SZ_RW)
#define SZ_SW    (NL * 16384)                 // [l][n=256][k=64]
#define OFF_W0   (OFF_SW + SZ_SW)             // [n=256][k=256]
#define OFF_W1   (OFF_W0 + 65536)             // [n=256][k=256]
#define TOTAL_W  (OFF_W1 + 65536)             // 1,236,992 elems (2.42 MB)

#define X_ELEMS  (NB * NT * NC)               // 2,097,152 (4 MB bf16)
#define WS_NEEDED ((size_t)(2 * X_ELEMS + TOTAL_W) * 2 + 257 * 4 + 64)

__device__ inline ushort_t f2bu(float f) {
  union { float f; unsigned u; } v; v.f = f;
  unsigned r = v.u + 0x7FFFu + ((v.u >> 16) & 1u);
  return (ushort_t)(r >> 16);
}
__device__ inline float b2f(ushort_t h) {
  union { unsigned u; float f; } v; v.u = ((unsigned)h) << 16; return v.f;
}

__global__ void sentinel_kernel(float* __restrict__ out) {
  if (threadIdx.x == 0) out[0] = -1234.0f;
}

// ---------------------------------------------------------------------------
// Whole WaveNet in one cooperative kernel.
// 256 blocks x 512 threads (8 waves). Block owns 128 positions; wave owns 16.
// Skip accumulator lives in registers (fp32) for all 30 layers.
// ---------------------------------------------------------------------------
__global__ __launch_bounds__(512, 2) void wavenet_fused(
    const int* __restrict__ wf, const int* __restrict__ lens,
    const float* __restrict__ embed,
    const float* __restrict__ cw, const float* __restrict__ cb_all,
    const float* __restrict__ rw, const float* __restrict__ rb_all,
    const float* __restrict__ sw, const float* __restrict__ sb_all,
    const float* __restrict__ w0, const float* __restrict__ b0,
    const float* __restrict__ w1, const float* __restrict__ b1,
    ushort_t* __restrict__ x0, ushort_t* __restrict__ x1,
    ushort_t* __restrict__ wt, float* __restrict__ sbsum,
    float* __restrict__ loss, float* __restrict__ out)
{
  cg::grid_group grid = cg::this_grid();

  // LDS: layer phase = lwc(32KB) + lrw(8KB) + gt(18KB) = 59392 B
  //      head phase  = tile 64x264 bf16 (33792 B) + red arrays (1536 B)
  __shared__ __align__(16) char smem[59392];
  ushort_t* lwc = (ushort_t*)smem;
  ushort_t* lrw = (ushort_t*)(smem + 32768);
  ushort_t (*gt)[72] = (ushort_t(*)[72])(smem + 40960);
  ushort_t (*tile)[264] = (ushort_t(*)[264])smem;
  float* redM = (float*)(smem + 33792);     // [2][64]
  float* redS = redM + 128;
  float* redT = redS + 128;

  const int tid = threadIdx.x;
  const int w = tid >> 6, lane = tid & 63;
  const int quad = lane >> 4, c16 = lane & 15;
  const int bb = blockIdx.x >> 6;           // 64 blocks per batch
  const int t0 = (blockIdx.x & 63) << 7;    // 128 positions per block
  const int mg = w;
  const int tb = t0 + mg * 16;              // wave row base

  // ======== phase 0: weight prep (transpose + bf16) + sbsum + loss=0 ========
  for (int idx = blockIdx.x * 512 + tid; idx < TOTAL_W + 257; idx += 256 * 512) {
    if (idx < TOTAL_W) {
      float v;
      if (idx < OFF_RW) {
        int e = idx; int l = e >> 14; int r = e & 16383;
        int kk = r >> 12; int n = (r >> 5) & 127; int j = r & 31;
        int k = kk * 32 + j; int tap = k >> 6; int c = k & 63;
        v = cw[(((l * 2 + tap) << 6) + c) * 128 + n];
      } else if (idx < OFF_SW) {
        int e = idx - OFF_RW; int l = e >> 12; int r = e & 4095;
        int kk = r >> 11; int n = (r >> 5) & 63; int j = r & 31;
        int k = kk * 32 + j;
        v = rw[((l << 6) + k) * 64 + n];
      } else if (idx < OFF_W0) {
        int e = idx - OFF_SW; int l = e >> 14; int r = e & 16383;
        int n = r >> 6; int k = r & 63;
        v = sw[((l << 6) + k) * 256 + n];
      } else if (idx < OFF_W1) {
        int e = idx - OFF_W0; int n = e >> 8; int k = e & 255;
        v = w0[k * 256 + n];
      } else {
        int e = idx - OFF_W1; int n = e >> 8; int k = e & 255;
        v = w1[k * 256 + n];
      }
      wt[idx] = f2bu(v);
    } else if (idx < TOTAL_W + 256) {
      int j = idx - TOTAL_W;
      float s = 0.f;
      for (int l = 0; l < NL; ++l) s += sb_all[l * 256 + j];
      sbsum[j] = s;
    } else {
      loss[0] = 0.f;
    }
  }

  // ======== phase 1: embedding for this block's 128 positions ========
#pragma unroll
  for (int i = 0; i < 16; ++i) {
    int e = tid + i * 512;
    int p = e >> 6, c = e & 63;
    int t = t0 + p;
    int id = (t == 0) ? 128 : wf[bb * NT + t - 1];
    x0[((size_t)(bb * NT + t)) * 64 + c] = f2bu(embed[id * 64 + c]);
  }
  __threadfence();
  grid.sync();

  // ======== phase 2: 30 layers, skip accumulator in registers ========
  f32x4 sacc[16];
#pragma unroll
  for (int nt = 0; nt < 16; ++nt) { f32x4 z = {0.f, 0.f, 0.f, 0.f}; sacc[nt] = z; }

  const ushort_t* xin = x0;
  ushort_t* xout = x1;

  for (int l = 0; l < NL; ++l) {
    int lm = l; while (lm >= 10) lm -= 10;
    const int d = 1 << lm;
    const ushort_t* wcat_s = wt + OFF_WCAT + l * 16384;
    const ushort_t* rw_s   = wt + OFF_RW + l * 4096;
    const ushort_t* swT    = wt + OFF_SW + l * 16384;
    const float* cb = cb_all + l * 128;
    const float* rb = rb_all + l * 64;

    // stage conv+res weights into LDS
    {
      bf16x8* dst = (bf16x8*)lwc;
      const bf16x8* s1 = (const bf16x8*)wcat_s;
#pragma unroll
      for (int i = 0; i < 4; ++i) dst[tid + i * 512] = s1[tid + i * 512];
      ((bf16x8*)lrw)[tid] = ((const bf16x8*)rw_s)[tid];
    }

    // A-fragments of [Xd | X]
    const int tA = tb + c16;
    bf16x8 af[4];
#pragma unroll
    for (int kk = 0; kk < 4; ++kk) {
      int ts = (kk < 2) ? (tA - d) : tA;
      int ch = (kk & 1) * 32 + quad * 8;
      if (ts >= 0) {
        af[kk] = *(const bf16x8*)(xin + ((size_t)(bb * NT + ts)) * 64 + ch);
      } else {
        bf16x8 z = {0, 0, 0, 0, 0, 0, 0, 0};
        af[kk] = z;
      }
    }
    __syncthreads();

    // GEMM1: H = [Xd|X] @ Wcat + cb ; gate -> LDS (wave-private rows)
#pragma unroll
    for (int q = 0; q < 4; ++q) {
      int na = q * 16 + c16;
      int nb2 = na + 64;
      float ba = cb[na], bs = cb[nb2];
      f32x4 va = {ba, ba, ba, ba}, vb = {bs, bs, bs, bs};
#pragma unroll
      for (int kk = 0; kk < 4; ++kk) {
        va = MFMA(af[kk], *(const bf16x8*)&lwc[kk * 4096 + na * 32 + quad * 8], va);
        vb = MFMA(af[kk], *(const bf16x8*)&lwc[kk * 4096 + nb2 * 32 + quad * 8], vb);
      }
#pragma unroll
      for (int r = 0; r < 4; ++r) {
        float e2 = __expf(2.f * va[r]);
        float th = (e2 - 1.f) / (e2 + 1.f);
        float sg = 1.f / (1.f + __expf(-vb[r]));
        gt[mg * 16 + quad * 4 + r][q * 16 + c16] = f2bu(th * sg);
      }
    }

    // gate A-fragments (same wave's rows -> only lgkmcnt needed)
    bf16x8 gf0 = *(const bf16x8*)&gt[mg * 16 + c16][quad * 8];
    bf16x8 gf1 = *(const bf16x8*)&gt[mg * 16 + c16][32 + quad * 8];

    // GEMM2: xout = x + gate @ RW + rb  (skipped for last layer: unused)
    if (l < NL - 1) {
#pragma unroll
      for (int q = 0; q < 4; ++q) {
        int n = q * 16 + c16;
        float bv = rb[n];
        f32x4 acc = {bv, bv, bv, bv};
        acc = MFMA(gf0, *(const bf16x8*)&lrw[n * 32 + quad * 8], acc);
        acc = MFMA(gf1, *(const bf16x8*)&lrw[2048 + n * 32 + quad * 8], acc);
#pragma unroll
        for (int r = 0; r < 4; ++r) {
          size_t idx = ((size_t)(bb * NT + tb + quad * 4 + r)) * 64 + n;
          xout[idx] = f2bu(b2f(xin[idx]) + acc[r]);
        }
      }
    }

    // GEMM3: skip accumulate in registers (MFMA accumulates in place)
#pragma unroll
    for (int nt = 0; nt < 16; ++nt) {
      int n = nt * 16 + c16;
      const ushort_t* wp = swT + n * 64 + quad * 8;
      sacc[nt] = MFMA(gf0, *(const bf16x8*)wp, sacc[nt]);
      sacc[nt] = MFMA(gf1, *(const bf16x8*)(wp + 32), sacc[nt]);
    }

    if (l < NL - 1) {
      __threadfence();
      grid.sync();
      const ushort_t* tmp = xout; xout = (ushort_t*)xin; xin = tmp;
    } else {
      __syncthreads();   // before head phase reuses LDS
    }
  }

  // ======== phase 3: head over two 64-row halves ========
  const ushort_t* w0T = wt + OFF_W0;
  const ushort_t* w1T = wt + OFF_W1;
  const int mylen = lens[bb];
  const int mg2 = w >> 1, nh = w & 1;

  for (int h = 0; h < 2; ++h) {
    // waves mg in [4h, 4h+4) dump their skip registers (+ sbsum) into LDS
    if ((mg >> 2) == h) {
      int lr0 = (mg & 3) * 16;
#pragma unroll
      for (int nt = 0; nt < 16; ++nt) {
        int n = nt * 16 + c16;
        float sbn = sbsum[n];
#pragma unroll
        for (int r = 0; r < 4; ++r)
          tile[lr0 + quad * 4 + r][n] = f2bu(sacc[nt][r] + sbn);
      }
    }
    __syncthreads();

    // A-fragments of skip tile
    bf16x8 haf[8];
#pragma unroll
    for (int kk = 0; kk < 8; ++kk)
      haf[kk] = *(const bf16x8*)&tile[mg2 * 16 + c16][kk * 32 + quad * 8];
    __syncthreads();

    // GEMM-A: hid = relu(skip @ w0 + b0) -> tile in place
#pragma unroll
    for (int nt = 0; nt < 8; ++nt) {
      int n = nh * 128 + nt * 16 + c16;
      float bv = b0[n];
      f32x4 acc = {bv, bv, bv, bv};
      const ushort_t* wp = w0T + n * 256 + quad * 8;
#pragma unroll
      for (int kk = 0; kk < 8; ++kk)
        acc = MFMA(haf[kk], *(const bf16x8*)(wp + kk * 32), acc);
#pragma unroll
      for (int r = 0; r < 4; ++r)
        tile[mg2 * 16 + quad * 4 + r][n] = f2bu(fmaxf(acc[r], 0.f));
    }
    __syncthreads();

    // hid A-fragments
    bf16x8 hf[8];
#pragma unroll
    for (int kk = 0; kk < 8; ++kk)
      hf[kk] = *(const bf16x8*)&tile[mg2 * 16 + c16][kk * 32 + quad * 8];

    int lblv[4];
#pragma unroll
    for (int r = 0; r < 4; ++r)
      lblv[r] = wf[bb * NT + t0 + h * 64 + mg2 * 16 + quad * 4 + r];

    // GEMM-B with online log-softmax over this wave's 128 columns
    float m_[4], s_[4], tg[4];
#pragma unroll
    for (int r = 0; r < 4; ++r) { m_[r] = -1e30f; s_[r] = 0.f; tg[r] = -1e30f; }

#pragma unroll
    for (int nt = 0; nt < 8; ++nt) {
      int n = nh * 128 + nt * 16 + c16;
      float bv = b1[n];
      f32x4 acc = {bv, bv, bv, bv};
      const ushort_t* wp = w1T + n * 256 + quad * 8;
#pragma unroll
      for (int kk = 0; kk < 8; ++kk)
        acc = MFMA(hf[kk], *(const bf16x8*)(wp + kk * 32), acc);
#pragma unroll
      for (int r = 0; r < 4; ++r) {
        float v = acc[r];
        float nm = fmaxf(m_[r], v);
        s_[r] = s_[r] * __expf(m_[r] - nm) + __expf(v - nm);
        m_[r] = nm;
        if (lblv[r] == n) tg[r] = v;
      }
    }

    // reduce across the 16 c16 lanes
#pragma unroll
    for (int r = 0; r < 4; ++r) {
      float m = m_[r], s = s_[r], tv = tg[r];
#pragma unroll
      for (int dd = 1; dd < 16; dd <<= 1) {
        float mo = __shfl_xor(m, dd);
        float so = __shfl_xor(s, dd);
        float to = __shfl_xor(tv, dd);
        float nm = fmaxf(m, mo);
        s = s * __expf(m - nm) + so * __expf(mo - nm);
        m = nm;
        tv = fmaxf(tv, to);
      }
      if (c16 == 0) {
        int row = mg2 * 16 + quad * 4 + r;
        redM[nh * 64 + row] = m; redS[nh * 64 + row] = s; redT[nh * 64 + row] = tv;
      }
    }
    __syncthreads();

    // combine column halves; CE; block partial -> atomic
    if (tid < 64) {
      int row = tid;
      float m0 = redM[row], m1 = redM[64 + row];
      float m = fmaxf(m0, m1);
      float s = redS[row] * __expf(m0 - m) + redS[64 + row] * __expf(m1 - m);
      float tv = fmaxf(redT[row], redT[64 + row]);
      float ce = 0.f;
      if (t0 + h * 64 + row < mylen) ce = (m + __logf(s)) - tv;
#pragma unroll
      for (int dd = 1; dd < 64; dd <<= 1) ce += __shfl_xor(ce, dd);
      if (tid == 0) atomicAdd(loss, ce);
    }
    __syncthreads();
  }

  // ======== phase 4: finalize ========
  __threadfence();
  grid.sync();
  if (blockIdx.x == 0 && tid == 0) {
    float den = 0.f;
    for (int b = 0; b < NB; ++b) {
      int lv = lens[b];
      if (lv > NT) lv = NT;
      den += (float)lv;
    }
    float tot = atomicAdd(loss, 0.0f);
    out[0] = tot / fmaxf(den, 1.f);
  }
}

// ---------------------------------------------------------------------------
extern "C" void kernel_launch(void* const* d_in, const int* in_sizes, int n_in,
                              void* d_out, int out_size, void* d_ws, size_t ws_size,
                              hipStream_t stream) {
  const int*   wf     = (const int*)d_in[0];
  const int*   lens   = (const int*)d_in[1];
  const float* embed  = (const float*)d_in[2];
  const float* conv_w = (const float*)d_in[3];
  const float* conv_b = (const float*)d_in[4];
  const float* res_w  = (const float*)d_in[5];
  const float* res_b  = (const float*)d_in[6];
  const float* skip_w = (const float*)d_in[7];
  const float* skip_b = (const float*)d_in[8];
  const float* w0     = (const float*)d_in[9];
  const float* b0     = (const float*)d_in[10];
  const float* w1     = (const float*)d_in[11];
  const float* b1     = (const float*)d_in[12];

  float* out = (float*)d_out;
  if (ws_size < WS_NEEDED) {
    sentinel_kernel<<<1, 64, 0, stream>>>(out);
    return;
  }

  ushort_t* x0 = (ushort_t*)d_ws;          // 4 MB bf16
  ushort_t* x1 = x0 + X_ELEMS;             // 4 MB bf16
  ushort_t* wt = x1 + X_ELEMS;             // 2.42 MB bf16
  float* sbsum = (float*)(wt + TOTAL_W);   // 1 KB
  float* loss  = sbsum + 256;              // 4 B

  void* args[] = {
    (void*)&wf, (void*)&lens, (void*)&embed,
    (void*)&conv_w, (void*)&conv_b, (void*)&res_w, (void*)&res_b,
    (void*)&skip_w, (void*)&skip_b, (void*)&w0, (void*)&b0,
    (void*)&w1, (void*)&b1,
    (void*)&x0, (void*)&x1, (void*)&wt, (void*)&sbsum, (void*)&loss,
    (void*)&out
  };
  hipLaunchCooperativeKernel((void*)wavenet_fused, dim3(256), dim3(512),
                             args, 0, stream);
}

// Round 7
// 1843.602 us; speedup vs baseline: 1.3290x; 1.3290x over previous
//
#include <hip/hip_runtime.h>
#include <hip/hip_cooperative_groups.h>

namespace cg = cooperative_groups;

#define NB 4
#define NT 8192
#define NC 64
#define NS 256
#define NV 256
#define NL 30

typedef __attribute__((ext_vector_type(8))) short bf16x8;
typedef __attribute__((ext_vector_type(4))) float f32x4;
typedef unsigned short ushort_t;

#define MFMA(a, b, c) __builtin_amdgcn_mfma_f32_16x16x32_bf16(a, b, c, 0, 0, 0)

// weight arena layout (bf16 elements)
#define OFF_WCAT 0
#define SZ_WCAT  (NL * 16384)                 // swizzled [l][kk=4][n=128][j=32]
#define OFF_RW   (OFF_WCAT + SZ_WCAT)
#define SZ_RW    (NL * 4096)                  // swizzled [l][kk=2][n=64][j=32]
#define OFF_SW   (OFF_RW + SZ_RW)
#define SZ_SW    (NL * 16384)                 // [l][n=256][k=64]
#define OFF_W0   (OFF_SW + SZ_SW)             // [n=256][k=256]
#define OFF_W1   (OFF_W0 + 65536)             // [n=256][k=256]
#define TOTAL_W  (OFF_W1 + 65536)             // 1,236,992 elems (2.42 MB)

#define X_ELEMS  (NB * NT * NC)               // 2,097,152 per slot (4 MB bf16)
#define NSLOT    8
#define FSTRIDE  32                           // flag padding: 128 B per flag
#define MAGICV   0x13570000u

#define WS_NEEDED ((size_t)(NSLOT * X_ELEMS + TOTAL_W) * 2 + \
                   (size_t)(256 + (256 + 33) * FSTRIDE + 256 + 64) * 4)

__device__ inline ushort_t f2bu(float f) {
  union { float f; unsigned u; } v; v.f = f;
  unsigned r = v.u + 0x7FFFu + ((v.u >> 16) & 1u);
  return (ushort_t)(r >> 16);
}
__device__ inline float b2f(ushort_t h) {
  union { unsigned u; float f; } v; v.u = ((unsigned)h) << 16; return v.f;
}
__device__ inline int dil_of(int l) {
  int m = l; if (m >= 20) m -= 20; else if (m >= 10) m -= 10;
  return 1 << m;
}
// Poison-safe spin: ready iff (value - MAGICV) in [need, 64]. 0xAAAAAAAA and 0
// both map far outside the window -> treated as "not ready". Bounded so a
// protocol bug fails loudly (wrong loss) instead of hanging the harness.
__device__ inline void wait_ge(unsigned* addr, unsigned need) {
  for (int i = 0; i < 10000000; ++i) {
    unsigned v = __hip_atomic_load(addr, __ATOMIC_ACQUIRE, __HIP_MEMORY_SCOPE_AGENT);
    unsigned c = v - MAGICV;
    if (c >= need && c <= 64u) return;
    __builtin_amdgcn_s_sleep(2);
  }
}
__device__ inline void post(unsigned* addr, unsigned s) {
  __hip_atomic_store(addr, MAGICV + s, __ATOMIC_RELEASE, __HIP_MEMORY_SCOPE_AGENT);
}

__global__ void sentinel_kernel(float* __restrict__ out) {
  if (threadIdx.x == 0) out[0] = -1234.0f;
}

// ---------------------------------------------------------------------------
// Whole WaveNet, one kernel, NO grid.sync. 256 blocks x 512 threads.
// Block owns a 128-position chunk for the whole net; deps flow via per-chunk
// release/acquire flags (<=4 upstream blocks per layer). Skip acc in regs.
// ---------------------------------------------------------------------------
__global__ __launch_bounds__(512, 2) void wavenet_pipe(
    const int* __restrict__ wf, const int* __restrict__ lens,
    const float* __restrict__ embed,
    const float* __restrict__ cw, const float* __restrict__ cb_all,
    const float* __restrict__ rw, const float* __restrict__ rb_all,
    const float* __restrict__ sw, const float* __restrict__ sb_all,
    const float* __restrict__ w0, const float* __restrict__ b0,
    const float* __restrict__ w1, const float* __restrict__ b1,
    ushort_t* __restrict__ xb, ushort_t* __restrict__ wt,
    float* __restrict__ sbsum, unsigned* __restrict__ stage,
    unsigned* __restrict__ prepF, float* __restrict__ cearr,
    float* __restrict__ out)
{
  __shared__ __align__(16) char smem[50176];
  ushort_t* lwc = (ushort_t*)smem;                        // 32 KB conv w
  ushort_t* lrw = (ushort_t*)(smem + 32768);              // 8 KB res w
  ushort_t (*gt)[72] = (ushort_t(*)[72])(smem + 40960);   // gate 64x72
  ushort_t (*tile)[264] = (ushort_t(*)[264])smem;         // head tile
  float* redM = (float*)(smem + 33792);
  float* redS = redM + 128;
  float* redT = redS + 128;

  const int tid = threadIdx.x;
  const int w = tid >> 6, lane = tid & 63;
  const int quad = lane >> 4, c16 = lane & 15;
  const int bid = blockIdx.x;
  // XCD-friendly chunk map: 8 consecutive chunks per XCD (flag partners local)
  const int xcd = bid & 7, sl = bid >> 3;
  const int bb = sl >> 3;
  const int cc = (xcd << 3) | (sl & 7);
  const int chunkid = (bb << 6) + cc;
  unsigned* myflag = stage + chunkid * FSTRIDE;
  const int t0 = cc << 7;                   // 128 positions per chunk
  const int mg = w;
  const int tb = t0 + mg * 16;              // wave row base

  // ======== embed own chunk -> slot 7 (acts as "layer -1" output) ========
  {
    ushort_t* x7 = xb + (size_t)7 * X_ELEMS;
#pragma unroll
    for (int i = 0; i < 16; ++i) {
      int e = tid + i * 512;
      int p = e >> 6, c = e & 63;
      int t = t0 + p;
      int id = (t == 0) ? 128 : wf[bb * NT + t - 1];
      x7[((size_t)(bb * NT + t)) * 64 + c] = f2bu(embed[id * 64 + c]);
    }
  }
  __threadfence();
  __syncthreads();
  if (tid == 0) post(myflag, 1u);

  // ======== weight prep: owner blocks 223..255 ========
  if (bid >= 223) {
    int o = bid - 223;   // 0..29 layer weights, 30 w0T, 31 w1T, 32 sbsum
    if (o < 30) {
      for (int e = tid; e < 36864; e += 512) {
        float v; int dst;
        if (e < 16384) {
          int r = e;
          int kk = r >> 12, n = (r >> 5) & 127, j = r & 31;
          int k = kk * 32 + j, tap = k >> 6, c = k & 63;
          v = cw[(((o * 2 + tap) << 6) + c) * 128 + n];
          dst = OFF_WCAT + o * 16384 + r;
        } else if (e < 20480) {
          int r = e - 16384;
          int kk = r >> 11, n = (r >> 5) & 63, j = r & 31;
          int k = kk * 32 + j;
          v = rw[((o << 6) + k) * 64 + n];
          dst = OFF_RW + o * 4096 + r;
        } else {
          int r = e - 20480;
          int n = r >> 6, k = r & 63;
          v = sw[((o << 6) + k) * 256 + n];
          dst = OFF_SW + o * 16384 + r;
        }
        wt[dst] = f2bu(v);
      }
    } else if (o == 30) {
      for (int e = tid; e < 65536; e += 512) {
        int n = e >> 8, k = e & 255;
        wt[OFF_W0 + e] = f2bu(w0[k * 256 + n]);
      }
    } else if (o == 31) {
      for (int e = tid; e < 65536; e += 512) {
        int n = e >> 8, k = e & 255;
        wt[OFF_W1 + e] = f2bu(w1[k * 256 + n]);
      }
    } else {
      for (int j = tid; j < 256; j += 512) {
        float s = 0.f;
        for (int l2 = 0; l2 < NL; ++l2) s += sb_all[l2 * 256 + j];
        sbsum[j] = s;
      }
    }
    __threadfence();
    __syncthreads();
    if (tid == 0) post(prepF + o * FSTRIDE, 1u);
  }

  // ======== 30 layers; skip accumulator in registers ========
  f32x4 sacc[16];
#pragma unroll
  for (int nt = 0; nt < 16; ++nt) { f32x4 z = {0.f, 0.f, 0.f, 0.f}; sacc[nt] = z; }

  for (int l = 0; l < NL; ++l) {
    const int d = dil_of(l);
    const int K = (d + 127) >> 7;   // upstream chunks needed
    const ushort_t* xin = xb + (size_t)((l + 7) & 7) * X_ELEMS;
    ushort_t* xout = xb + (size_t)(l & 7) * X_ELEMS;
    const ushort_t* wcat_s = wt + OFF_WCAT + l * 16384;
    const ushort_t* rw_s   = wt + OFF_RW + l * 4096;
    const ushort_t* swT    = wt + OFF_SW + l * 16384;
    const float* cb = cb_all + l * 128;
    const float* rb = rb_all + l * 64;

    // -- waits (designated threads), then barrier --
    if (tid < K) {                        // producers of my left halo
      int up = cc - 1 - tid;
      if (up >= 0) wait_ge(stage + ((bb << 6) + up) * FSTRIDE, (unsigned)(l + 1));
    }
    if (l >= 7 && tid >= 64 && tid < 68) {  // slot-reuse backpressure
      int dp = dil_of(l - 7);
      int Kp = (dp + 127) >> 7;
      int k2 = tid - 64;
      if (k2 < Kp) {
        int fw = cc + 1 + k2;
        if (fw < 64) wait_ge(stage + ((bb << 6) + fw) * FSTRIDE, (unsigned)(l - 5));
      }
    }
    if (tid == 128) wait_ge(prepF + l * FSTRIDE, 1u);
    __syncthreads();

    // -- stage conv+res weights into LDS --
    {
      bf16x8* dst = (bf16x8*)lwc;
      const bf16x8* s1 = (const bf16x8*)wcat_s;
#pragma unroll
      for (int i = 0; i < 4; ++i) dst[tid + i * 512] = s1[tid + i * 512];
      ((bf16x8*)lrw)[tid] = ((const bf16x8*)rw_s)[tid];
    }

    // -- A-fragments of [Xd | X] --
    const int tA = tb + c16;
    bf16x8 af[4];
#pragma unroll
    for (int kk = 0; kk < 4; ++kk) {
      int ts = (kk < 2) ? (tA - d) : tA;
      int ch = (kk & 1) * 32 + quad * 8;
      if (ts >= 0) {
        af[kk] = *(const bf16x8*)(xin + ((size_t)(bb * NT + ts)) * 64 + ch);
      } else {
        bf16x8 z = {0, 0, 0, 0, 0, 0, 0, 0};
        af[kk] = z;
      }
    }
    __syncthreads();

    // -- GEMM1: H = [Xd|X] @ Wcat + cb ; gate -> LDS (wave-private rows) --
#pragma unroll
    for (int q = 0; q < 4; ++q) {
      int na = q * 16 + c16;
      int nb2 = na + 64;
      float ba = cb[na], bs = cb[nb2];
      f32x4 va = {ba, ba, ba, ba}, vb = {bs, bs, bs, bs};
#pragma unroll
      for (int kk = 0; kk < 4; ++kk) {
        va = MFMA(af[kk], *(const bf16x8*)&lwc[kk * 4096 + na * 32 + quad * 8], va);
        vb = MFMA(af[kk], *(const bf16x8*)&lwc[kk * 4096 + nb2 * 32 + quad * 8], vb);
      }
#pragma unroll
      for (int r = 0; r < 4; ++r) {
        float e2 = __expf(2.f * va[r]);
        float th = (e2 - 1.f) / (e2 + 1.f);
        float sg = 1.f / (1.f + __expf(-vb[r]));
        gt[mg * 16 + quad * 4 + r][q * 16 + c16] = f2bu(th * sg);
      }
    }

    bf16x8 gf0 = *(const bf16x8*)&gt[mg * 16 + c16][quad * 8];
    bf16x8 gf1 = *(const bf16x8*)&gt[mg * 16 + c16][32 + quad * 8];

    // -- GEMM2: xout = x + gate @ RW + rb (last layer's output is unused) --
    if (l < NL - 1) {
#pragma unroll
      for (int q = 0; q < 4; ++q) {
        int n = q * 16 + c16;
        float bv = rb[n];
        f32x4 acc = {bv, bv, bv, bv};
        acc = MFMA(gf0, *(const bf16x8*)&lrw[n * 32 + quad * 8], acc);
        acc = MFMA(gf1, *(const bf16x8*)&lrw[2048 + n * 32 + quad * 8], acc);
#pragma unroll
        for (int r = 0; r < 4; ++r) {
          size_t idx = ((size_t)(bb * NT + tb + quad * 4 + r)) * 64 + n;
          xout[idx] = f2bu(b2f(xin[idx]) + acc[r]);
        }
      }
    }

    // -- GEMM3: skip accumulate in registers --
#pragma unroll
    for (int nt = 0; nt < 16; ++nt) {
      int n = nt * 16 + c16;
      const ushort_t* wp = swT + n * 64 + quad * 8;
      sacc[nt] = MFMA(gf0, *(const bf16x8*)wp, sacc[nt]);
      sacc[nt] = MFMA(gf1, *(const bf16x8*)(wp + 32), sacc[nt]);
    }

    if (l < NL - 1) {
      __threadfence();
      __syncthreads();
      if (tid == 0) post(myflag, (unsigned)(l + 2));
    } else {
      __syncthreads();   // LDS reuse before head
    }
  }

  // ======== head over two 64-row halves (block-local) ========
  if (tid < 3) wait_ge(prepF + (30 + tid) * FSTRIDE, 1u);
  __syncthreads();

  const ushort_t* w0T = wt + OFF_W0;
  const ushort_t* w1T = wt + OFF_W1;
  const int mylen = lens[bb];
  const int mg2 = w >> 1, nh = w & 1;
  float ce_blk = 0.f;   // meaningful on tid 0

  for (int h = 0; h < 2; ++h) {
    if ((mg >> 2) == h) {
      int lr0 = (mg & 3) * 16;
#pragma unroll
      for (int nt = 0; nt < 16; ++nt) {
        int n = nt * 16 + c16;
        float sbn = sbsum[n];
#pragma unroll
        for (int r = 0; r < 4; ++r)
          tile[lr0 + quad * 4 + r][n] = f2bu(sacc[nt][r] + sbn);
      }
    }
    __syncthreads();

    bf16x8 haf[8];
#pragma unroll
    for (int kk = 0; kk < 8; ++kk)
      haf[kk] = *(const bf16x8*)&tile[mg2 * 16 + c16][kk * 32 + quad * 8];
    __syncthreads();

    // GEMM-A: hid = relu(skip @ w0 + b0) -> tile in place
#pragma unroll
    for (int nt = 0; nt < 8; ++nt) {
      int n = nh * 128 + nt * 16 + c16;
      float bv = b0[n];
      f32x4 acc = {bv, bv, bv, bv};
      const ushort_t* wp = w0T + n * 256 + quad * 8;
#pragma unroll
      for (int kk = 0; kk < 8; ++kk)
        acc = MFMA(haf[kk], *(const bf16x8*)(wp + kk * 32), acc);
#pragma unroll
      for (int r = 0; r < 4; ++r)
        tile[mg2 * 16 + quad * 4 + r][n] = f2bu(fmaxf(acc[r], 0.f));
    }
    __syncthreads();

    bf16x8 hf[8];
#pragma unroll
    for (int kk = 0; kk < 8; ++kk)
      hf[kk] = *(const bf16x8*)&tile[mg2 * 16 + c16][kk * 32 + quad * 8];

    int lblv[4];
#pragma unroll
    for (int r = 0; r < 4; ++r)
      lblv[r] = wf[bb * NT + t0 + h * 64 + mg2 * 16 + quad * 4 + r];

    float m_[4], s_[4], tg[4];
#pragma unroll
    for (int r = 0; r < 4; ++r) { m_[r] = -1e30f; s_[r] = 0.f; tg[r] = -1e30f; }

#pragma unroll
    for (int nt = 0; nt < 8; ++nt) {
      int n = nh * 128 + nt * 16 + c16;
      float bv = b1[n];
      f32x4 acc = {bv, bv, bv, bv};
      const ushort_t* wp = w1T + n * 256 + quad * 8;
#pragma unroll
      for (int kk = 0; kk < 8; ++kk)
        acc = MFMA(hf[kk], *(const bf16x8*)(wp + kk * 32), acc);
#pragma unroll
      for (int r = 0; r < 4; ++r) {
        float v = acc[r];
        float nm = fmaxf(m_[r], v);
        s_[r] = s_[r] * __expf(m_[r] - nm) + __expf(v - nm);
        m_[r] = nm;
        if (lblv[r] == n) tg[r] = v;
      }
    }

#pragma unroll
    for (int r = 0; r < 4; ++r) {
      float m = m_[r], s = s_[r], tv = tg[r];
#pragma unroll
      for (int dd = 1; dd < 16; dd <<= 1) {
        float mo = __shfl_xor(m, dd);
        float so = __shfl_xor(s, dd);
        float to = __shfl_xor(tv, dd);
        float nm = fmaxf(m, mo);
        s = s * __expf(m - nm) + so * __expf(mo - nm);
        m = nm;
        tv = fmaxf(tv, to);
      }
      if (c16 == 0) {
        int row = mg2 * 16 + quad * 4 + r;
        redM[nh * 64 + row] = m; redS[nh * 64 + row] = s; redT[nh * 64 + row] = tv;
      }
    }
    __syncthreads();

    if (tid < 64) {
      int row = tid;
      float m0 = redM[row], m1 = redM[64 + row];
      float m = fmaxf(m0, m1);
      float s = redS[row] * __expf(m0 - m) + redS[64 + row] * __expf(m1 - m);
      float tv = fmaxf(redT[row], redT[64 + row]);
      float cev = 0.f;
      if (t0 + h * 64 + row < mylen) cev = (m + __logf(s)) - tv;
#pragma unroll
      for (int dd = 1; dd < 64; dd <<= 1) cev += __shfl_xor(cev, dd);
      if (tid == 0) ce_blk += cev;
    }
    __syncthreads();
  }

  if (tid == 0) cearr[chunkid] = ce_blk;
  __threadfence();
  __syncthreads();
  if (tid == 0) post(myflag, 32u);

  // ======== finalize: block 0 gathers all 256 CE partials ========
  if (bid == 0) {
    if (tid < 256) wait_ge(stage + tid * FSTRIDE, 32u);
    __syncthreads();
    if (tid < 64) {
      float s2 = cearr[tid] + cearr[tid + 64] + cearr[tid + 128] + cearr[tid + 192];
#pragma unroll
      for (int dd = 1; dd < 64; dd <<= 1) s2 += __shfl_xor(s2, dd);
      if (tid == 0) {
        float den = 0.f;
        for (int b = 0; b < NB; ++b) {
          int lv = lens[b];
          if (lv > NT) lv = NT;
          den += (float)lv;
        }
        out[0] = s2 / fmaxf(den, 1.f);
      }
    }
  }
}

// ---------------------------------------------------------------------------
extern "C" void kernel_launch(void* const* d_in, const int* in_sizes, int n_in,
                              void* d_out, int out_size, void* d_ws, size_t ws_size,
                              hipStream_t stream) {
  const int*   wf     = (const int*)d_in[0];
  const int*   lens   = (const int*)d_in[1];
  const float* embed  = (const float*)d_in[2];
  const float* conv_w = (const float*)d_in[3];
  const float* conv_b = (const float*)d_in[4];
  const float* res_w  = (const float*)d_in[5];
  const float* res_b  = (const float*)d_in[6];
  const float* skip_w = (const float*)d_in[7];
  const float* skip_b = (const float*)d_in[8];
  const float* w0     = (const float*)d_in[9];
  const float* b0     = (const float*)d_in[10];
  const float* w1     = (const float*)d_in[11];
  const float* b1     = (const float*)d_in[12];

  float* out = (float*)d_out;
  if (ws_size < WS_NEEDED) {
    sentinel_kernel<<<1, 64, 0, stream>>>(out);
    return;
  }

  ushort_t* xb    = (ushort_t*)d_ws;                    // 8 slots x 4 MB
  ushort_t* wt    = xb + (size_t)NSLOT * X_ELEMS;       // 2.42 MB
  float*    sbsum = (float*)(wt + TOTAL_W);             // 1 KB
  unsigned* stage = (unsigned*)(sbsum + 256);           // 256 flags, padded
  unsigned* prepF = stage + 256 * FSTRIDE;              // 33 flags, padded
  float*    cearr = (float*)(prepF + 33 * FSTRIDE);     // 256 CE partials

  void* args[] = {
    (void*)&wf, (void*)&lens, (void*)&embed,
    (void*)&conv_w, (void*)&conv_b, (void*)&res_w, (void*)&res_b,
    (void*)&skip_w, (void*)&skip_b, (void*)&w0, (void*)&b0,
    (void*)&w1, (void*)&b1,
    (void*)&xb, (void*)&wt, (void*)&sbsum, (void*)&stage, (void*)&prepF,
    (void*)&cearr, (void*)&out
  };
  hipLaunchCooperativeKernel((void*)wavenet_pipe, dim3(256), dim3(512),
                             args, 0, stream);
}

// Round 8
// 765.592 us; speedup vs baseline: 3.2003x; 2.4081x over previous
//
#include <hip/hip_runtime.h>

#define NB 4
#define NT 8192
#define NC 64
#define NS 256
#define NV 256
#define NL 30

typedef __attribute__((ext_vector_type(8))) short bf16x8;
typedef __attribute__((ext_vector_type(4))) float f32x4;
typedef unsigned short ushort_t;

#define MFMA(a, b, c) __builtin_amdgcn_mfma_f32_16x16x32_bf16(a, b, c, 0, 0, 0)

// weight arena (bf16 elems)
#define OFF_WCAT 0
#define SZ_WCAT  (NL * 16384)            // swizzled [l][kk=4][n=128][j=32]
#define OFF_RW   (OFF_WCAT + SZ_WCAT)
#define SZ_RW    (NL * 4096)             // swizzled [l][kk=2][n=64][j=32]
#define OFF_SWG  (OFF_RW + SZ_RW)
#define SZ_SWG   (6 * 81920)             // per group g: [n=256][k=320]
#define OFF_W0   (OFF_SWG + SZ_SWG)      // [n=256][k=256]
#define OFF_W1   (OFF_W0 + 65536)
#define TOTAL_W  (OFF_W1 + 65536)        // 1,236,992 elems (2.42 MB)
#define N_PREP   (TOTAL_W + 1536)        // + sbsum_g[6][256] fp32

#define X_ELEMS  (NB * NT * NC)          // 2,097,152 (4 MB bf16)
#define SK_ELEMS (NB * NT * NS)          // 8,388,608 (16 MB bf16)
#define G_ELEMS  (NB * NT * NC)          // gate slot (4 MB bf16)
#define WS_NEEDED ((size_t)(2 * X_ELEMS + SK_ELEMS + 5 * G_ELEMS + TOTAL_W) * 2 \
                   + 1536 * 4)           // 46.4 MB

__device__ inline ushort_t f2bu(float f) {
  union { float f; unsigned u; } v; v.f = f;
  unsigned r = v.u + 0x7FFFu + ((v.u >> 16) & 1u);
  return (ushort_t)(r >> 16);
}
__device__ inline float b2f(ushort_t h) {
  union { unsigned u; float f; } v; v.u = ((unsigned)h) << 16; return v.f;
}

__global__ void sentinel_kernel(float* __restrict__ out) {
  if (threadIdx.x == 0) out[0] = -1234.0f;
}
__global__ void zero_kernel(float* __restrict__ out) {
  if (threadIdx.x == 0) out[0] = 0.0f;
}

// ---------------------------------------------------------------------------
// Weight prep: conv/res swizzled for LDS B-frags; skip weights regrouped as
// 6 groups x [n=256][k=320] (k = group-local layer*64 + chan); w0/w1 as
// [n][k]; sbsum_g = per-group skip-bias sums.
// ---------------------------------------------------------------------------
__global__ __launch_bounds__(256) void prep_kernel(
    const float* __restrict__ cw, const float* __restrict__ rw,
    const float* __restrict__ sw, const float* __restrict__ w0,
    const float* __restrict__ w1, const float* __restrict__ sb_all,
    ushort_t* __restrict__ wt, float* __restrict__ sbg)
{
  int idx = blockIdx.x * 256 + threadIdx.x;
  if (idx >= N_PREP) return;
  if (idx >= TOTAL_W) {
    int j = idx - TOTAL_W;
    int g = j >> 8, n = j & 255;
    float s = 0.f;
#pragma unroll
    for (int jj = 0; jj < 5; ++jj) s += sb_all[(5 * g + jj) * 256 + n];
    sbg[j] = s;
    return;
  }
  float v;
  if (idx < OFF_RW) {
    int e = idx; int l = e >> 14; int r = e & 16383;
    int kk = r >> 12, n = (r >> 5) & 127, j = r & 31;
    int k = kk * 32 + j, tap = k >> 6, c = k & 63;
    v = cw[(((l * 2 + tap) << 6) + c) * 128 + n];
  } else if (idx < OFF_SWG) {
    int e = idx - OFF_RW; int l = e >> 12; int r = e & 4095;
    int kk = r >> 11, n = (r >> 5) & 63, j = r & 31;
    int k = kk * 32 + j;
    v = rw[((l << 6) + k) * 64 + n];
  } else if (idx < OFF_W0) {
    int e = idx - OFF_SWG; int g = e / 81920; int r = e % 81920;
    int n = r / 320, k = r % 320;
    v = sw[(size_t)(320 * g + k) * 256 + n];
  } else if (idx < OFF_W1) {
    int e = idx - OFF_W0; int n = e >> 8, k = e & 255;
    v = w0[k * 256 + n];
  } else {
    int e = idx - OFF_W1; int n = e >> 8, k = e & 255;
    v = w1[k * 256 + n];
  }
  wt[idx] = f2bu(v);
}

// ---------------------------------------------------------------------------
__global__ __launch_bounds__(256) void embed_kernel(
    const int* __restrict__ wf, const float* __restrict__ embed,
    ushort_t* __restrict__ x0)
{
  const int bidx = blockIdx.x;
  const int bb = bidx >> 7;
  const int t0 = (bidx & 127) << 6;
  const int pos0 = bb * NT + t0;
  for (int e = threadIdx.x; e < 64 * 64; e += 256) {
    int p = e >> 6, c = e & 63;
    int t = t0 + p;
    int id = (t == 0) ? 128 : wf[bb * NT + t - 1];
    x0[(size_t)(pos0 + p) * NC + c] = f2bu(embed[id * NC + c]);
  }
}

// ---------------------------------------------------------------------------
// Layer: conv(k=2,d) -> gate -> (gate to global slot) + residual x update.
// 512 blocks x 256 threads (4 waves); block owns 64 positions; wave owns 16.
// ---------------------------------------------------------------------------
__global__ __launch_bounds__(256, 4) void layer_kernel(
    const ushort_t* __restrict__ xin, ushort_t* __restrict__ xout,
    ushort_t* __restrict__ gate_out,
    const ushort_t* __restrict__ wcat_s, const float* __restrict__ cb,
    const ushort_t* __restrict__ rw_s,   const float* __restrict__ rb,
    int d, int write_res)
{
  __shared__ __align__(16) char smem[59392];
  ushort_t* lwc = (ushort_t*)smem;                        // 32 KB
  ushort_t* lrw = (ushort_t*)(smem + 32768);              // 8 KB
  ushort_t (*gt)[72] = (ushort_t(*)[72])(smem + 40960);   // 64x72 (18 KB)

  const int tid = threadIdx.x;
  const int w = tid >> 6, lane = tid & 63;
  const int quad = lane >> 4, c16 = lane & 15;
  const int bb = blockIdx.x >> 7;
  const int t0 = (blockIdx.x & 127) << 6;
  const int tb = t0 + w * 16;
  const size_t row0 = (size_t)bb * NT;

  // stage weights into LDS
  {
    bf16x8* dst = (bf16x8*)lwc;
    const bf16x8* s1 = (const bf16x8*)wcat_s;
#pragma unroll
    for (int i = 0; i < 8; ++i) dst[tid + i * 256] = s1[tid + i * 256];
    bf16x8* dst2 = (bf16x8*)lrw;
    const bf16x8* s2 = (const bf16x8*)rw_s;
#pragma unroll
    for (int i = 0; i < 2; ++i) dst2[tid + i * 256] = s2[tid + i * 256];
  }

  // A-fragments of [Xd | X]
  const int tA = tb + c16;
  bf16x8 af[4];
#pragma unroll
  for (int kk = 0; kk < 4; ++kk) {
    int ts = (kk < 2) ? (tA - d) : tA;
    int ch = (kk & 1) * 32 + quad * 8;
    if (ts >= 0) {
      af[kk] = *(const bf16x8*)(xin + (row0 + ts) * 64 + ch);
    } else {
      bf16x8 z = {0, 0, 0, 0, 0, 0, 0, 0};
      af[kk] = z;
    }
  }
  __syncthreads();

  // GEMM1: H = [Xd|X] @ Wcat + cb ; gate -> LDS (wave-private rows)
#pragma unroll
  for (int q = 0; q < 4; ++q) {
    int na = q * 16 + c16;
    int nb2 = na + 64;
    float ba = cb[na], bs = cb[nb2];
    f32x4 va = {ba, ba, ba, ba}, vb = {bs, bs, bs, bs};
#pragma unroll
    for (int kk = 0; kk < 4; ++kk) {
      va = MFMA(af[kk], *(const bf16x8*)&lwc[kk * 4096 + na * 32 + quad * 8], va);
      vb = MFMA(af[kk], *(const bf16x8*)&lwc[kk * 4096 + nb2 * 32 + quad * 8], vb);
    }
#pragma unroll
    for (int r = 0; r < 4; ++r) {
      float e2 = __expf(2.f * va[r]);
      float th = (e2 - 1.f) / (e2 + 1.f);
      float sg = 1.f / (1.f + __expf(-vb[r]));
      gt[w * 16 + quad * 4 + r][q * 16 + c16] = f2bu(th * sg);
    }
  }

  // gate A-fragments (own wave's rows, no barrier)
  bf16x8 gf0 = *(const bf16x8*)&gt[w * 16 + c16][quad * 8];
  bf16x8 gf1 = *(const bf16x8*)&gt[w * 16 + c16][32 + quad * 8];

  // GEMM2: xout = x + gate @ RW + rb
  if (write_res) {
#pragma unroll
    for (int q = 0; q < 4; ++q) {
      int n = q * 16 + c16;
      float bv = rb[n];
      f32x4 acc = {bv, bv, bv, bv};
      acc = MFMA(gf0, *(const bf16x8*)&lrw[n * 32 + quad * 8], acc);
      acc = MFMA(gf1, *(const bf16x8*)&lrw[2048 + n * 32 + quad * 8], acc);
#pragma unroll
      for (int r = 0; r < 4; ++r) {
        size_t idx = (row0 + tb + quad * 4 + r) * 64 + n;
        xout[idx] = f2bu(b2f(xin[idx]) + acc[r]);
      }
    }
  }

  // cooperative vectorized gate write: LDS -> global slot
  __syncthreads();
#pragma unroll
  for (int i = 0; i < 2; ++i) {
    int e = tid + i * 256;              // 512 x 8-elem groups
    int rrow = e >> 3, c0 = (e & 7) * 8;
    bf16x8 v = *(const bf16x8*)&gt[rrow][c0];
    *(bf16x8*)(gate_out + (row0 + t0 + rrow) * 64 + c0) = v;
  }
}

// ---------------------------------------------------------------------------
// Skip-group GEMM: skip += gates[0..4] @ SWcat_g + sbsum_g.  K = 320.
// 512 blocks x 256 threads; block owns 64 positions; wave owns 16 rows.
// ---------------------------------------------------------------------------
__global__ __launch_bounds__(256, 2) void skip_kernel(
    ushort_t* __restrict__ skip, const ushort_t* __restrict__ gates,
    const ushort_t* __restrict__ swg, const float* __restrict__ sbg,
    int first)
{
  const int tid = threadIdx.x;
  const int w = tid >> 6, lane = tid & 63;
  const int quad = lane >> 4, c16 = lane & 15;
  const int bb = blockIdx.x >> 7;
  const int t0 = (blockIdx.x & 127) << 6;
  const int tb = t0 + w * 16;
  const size_t row0 = (size_t)bb * NT;

  f32x4 acc[16];
#pragma unroll
  for (int nt = 0; nt < 16; ++nt) { f32x4 z = {0.f, 0.f, 0.f, 0.f}; acc[nt] = z; }

  const size_t arow = (row0 + tb + c16) * 64;
#pragma unroll
  for (int kk = 0; kk < 10; ++kk) {
    int slot = kk >> 1;
    bf16x8 af = *(const bf16x8*)(gates + (size_t)slot * G_ELEMS + arow +
                                 (kk & 1) * 32 + quad * 8);
#pragma unroll
    for (int nt = 0; nt < 16; ++nt) {
      int n = nt * 16 + c16;
      bf16x8 bf = *(const bf16x8*)(swg + n * 320 + kk * 32 + quad * 8);
      acc[nt] = MFMA(af, bf, acc[nt]);
    }
  }

#pragma unroll
  for (int nt = 0; nt < 16; ++nt) {
    int n = nt * 16 + c16;
    float sbn = sbg[n];
#pragma unroll
    for (int r = 0; r < 4; ++r) {
      size_t idx = (row0 + tb + quad * 4 + r) * 256 + n;
      float old = first ? 0.f : b2f(skip[idx]);
      skip[idx] = f2bu(old + acc[nt][r] + sbn);
    }
  }
}

// ---------------------------------------------------------------------------
// Head: relu(skip@w0+b0)@w1+b1 -> log_softmax -> masked CE (atomic to out).
// 512 blocks x 256 threads; block 64 positions; wave owns 16 rows x all 256 n.
// ---------------------------------------------------------------------------
__global__ __launch_bounds__(256, 2) void head_kernel(
    const ushort_t* __restrict__ skip,
    const ushort_t* __restrict__ w0T, const float* __restrict__ b0,
    const ushort_t* __restrict__ w1T, const float* __restrict__ b1,
    const int* __restrict__ wf, const int* __restrict__ lens,
    float* __restrict__ loss)
{
  __shared__ __align__(16) ushort_t tile[64][264];
  const int tid = threadIdx.x;
  const int w = tid >> 6, lane = tid & 63;
  const int quad = lane >> 4, c16 = lane & 15;
  const int bb = blockIdx.x >> 7;
  const int t0 = (blockIdx.x & 127) << 6;
  const int tb = t0 + w * 16;
  const size_t row0 = (size_t)bb * NT;
  const int mylen = lens[bb];

  // skip A-fragments
  bf16x8 af[8];
  const ushort_t* sp = skip + (row0 + tb + c16) * 256 + quad * 8;
#pragma unroll
  for (int kk = 0; kk < 8; ++kk)
    af[kk] = *(const bf16x8*)(sp + kk * 32);

  // GEMM-A: hid = relu(skip @ w0 + b0) -> tile (wave-private rows)
#pragma unroll
  for (int nt = 0; nt < 16; ++nt) {
    int n = nt * 16 + c16;
    float bv = b0[n];
    f32x4 acc = {bv, bv, bv, bv};
    const ushort_t* wp = w0T + n * 256 + quad * 8;
#pragma unroll
    for (int kk = 0; kk < 8; ++kk)
      acc = MFMA(af[kk], *(const bf16x8*)(wp + kk * 32), acc);
#pragma unroll
    for (int r = 0; r < 4; ++r)
      tile[w * 16 + quad * 4 + r][n] = f2bu(fmaxf(acc[r], 0.f));
  }

  // hid A-fragments (own rows, no barrier)
  bf16x8 hf[8];
#pragma unroll
  for (int kk = 0; kk < 8; ++kk)
    hf[kk] = *(const bf16x8*)&tile[w * 16 + c16][kk * 32 + quad * 8];

  int lblv[4];
#pragma unroll
  for (int r = 0; r < 4; ++r)
    lblv[r] = wf[row0 + tb + quad * 4 + r];

  // GEMM-B with online log-softmax over all 256 columns
  float m_[4], s_[4], tg[4];
#pragma unroll
  for (int r = 0; r < 4; ++r) { m_[r] = -1e30f; s_[r] = 0.f; tg[r] = -1e30f; }

#pragma unroll
  for (int nt = 0; nt < 16; ++nt) {
    int n = nt * 16 + c16;
    float bv = b1[n];
    f32x4 acc = {bv, bv, bv, bv};
    const ushort_t* wp = w1T + n * 256 + quad * 8;
#pragma unroll
    for (int kk = 0; kk < 8; ++kk)
      acc = MFMA(hf[kk], *(const bf16x8*)(wp + kk * 32), acc);
#pragma unroll
    for (int r = 0; r < 4; ++r) {
      float v = acc[r];
      float nm = fmaxf(m_[r], v);
      s_[r] = s_[r] * __expf(m_[r] - nm) + __expf(v - nm);
      m_[r] = nm;
      if (lblv[r] == n) tg[r] = v;
    }
  }

  // 16-lane butterfly (c16 dimension); CE per row; wave reduce; atomic
  float local = 0.f;
#pragma unroll
  for (int r = 0; r < 4; ++r) {
    float m = m_[r], s = s_[r], tv = tg[r];
#pragma unroll
    for (int dd = 1; dd < 16; dd <<= 1) {
      float mo = __shfl_xor(m, dd);
      float so = __shfl_xor(s, dd);
      float to = __shfl_xor(tv, dd);
      float nm = fmaxf(m, mo);
      s = s * __expf(m - nm) + so * __expf(mo - nm);
      m = nm;
      tv = fmaxf(tv, to);
    }
    int t = tb + quad * 4 + r;
    if (c16 == 0 && t < mylen) local += (m + __logf(s)) - tv;
  }
#pragma unroll
  for (int dd = 1; dd < 64; dd <<= 1) local += __shfl_xor(local, dd);
  if (lane == 0 && local != 0.f) atomicAdd(loss, local);
}

__global__ void finalize_kernel(const int* __restrict__ lens,
                                float* __restrict__ out)
{
  if (threadIdx.x == 0) {
    float den = 0.f;
    for (int b = 0; b < NB; ++b) {
      int l = lens[b];
      if (l > NT) l = NT;
      den += (float)l;
    }
    out[0] = out[0] / fmaxf(den, 1.f);
  }
}

// ---------------------------------------------------------------------------
extern "C" void kernel_launch(void* const* d_in, const int* in_sizes, int n_in,
                              void* d_out, int out_size, void* d_ws, size_t ws_size,
                              hipStream_t stream) {
  const int*   wf     = (const int*)d_in[0];
  const int*   lens   = (const int*)d_in[1];
  const float* embed  = (const float*)d_in[2];
  const float* conv_w = (const float*)d_in[3];
  const float* conv_b = (const float*)d_in[4];
  const float* res_w  = (const float*)d_in[5];
  const float* res_b  = (const float*)d_in[6];
  const float* skip_w = (const float*)d_in[7];
  const float* skip_b = (const float*)d_in[8];
  const float* w0     = (const float*)d_in[9];
  const float* b0     = (const float*)d_in[10];
  const float* w1     = (const float*)d_in[11];
  const float* b1     = (const float*)d_in[12];

  float* out = (float*)d_out;
  if (ws_size < WS_NEEDED) {
    sentinel_kernel<<<1, 64, 0, stream>>>(out);
    return;
  }

  ushort_t* x0    = (ushort_t*)d_ws;            // 4 MB
  ushort_t* x1    = x0 + X_ELEMS;               // 4 MB
  ushort_t* skip  = x1 + X_ELEMS;               // 16 MB
  ushort_t* gates = skip + SK_ELEMS;            // 5 x 4 MB
  ushort_t* wt    = gates + 5 * (size_t)G_ELEMS;// 2.42 MB
  float*    sbg   = (float*)(wt + TOTAL_W);     // 6 KB

  prep_kernel<<<(N_PREP + 255) / 256, 256, 0, stream>>>(
      conv_w, res_w, skip_w, w0, w1, skip_b, wt, sbg);
  embed_kernel<<<512, 256, 0, stream>>>(wf, embed, x0);
  zero_kernel<<<1, 64, 0, stream>>>(out);

  static const int dil[NL] = {1, 2, 4, 8, 16, 32, 64, 128, 256, 512,
                              1, 2, 4, 8, 16, 32, 64, 128, 256, 512,
                              1, 2, 4, 8, 16, 32, 64, 128, 256, 512};
  const ushort_t* xin = x0;
  ushort_t* xout = x1;
  for (int l = 0; l < NL; ++l) {
    layer_kernel<<<512, 256, 0, stream>>>(
        xin, xout, gates + (size_t)(l % 5) * G_ELEMS,
        wt + OFF_WCAT + l * 16384, conv_b + l * 128,
        wt + OFF_RW + l * 4096,    res_b + l * 64,
        dil[l], l < NL - 1 ? 1 : 0);
    if (l % 5 == 4) {
      int g = l / 5;
      skip_kernel<<<512, 256, 0, stream>>>(
          skip, gates, wt + OFF_SWG + g * 81920, sbg + g * 256, g == 0 ? 1 : 0);
    }
    const ushort_t* t = xout; xout = (ushort_t*)xin; xin = t;
  }

  head_kernel<<<512, 256, 0, stream>>>(skip, wt + OFF_W0, b0, wt + OFF_W1, b1,
                                       wf, lens, out);
  finalize_kernel<<<1, 64, 0, stream>>>(lens, out);
}